// Round 12
// baseline (317.863 us; speedup 1.0000x reference)
//
#include <hip/hip_runtime.h>
#include <hip/hip_bf16.h>

typedef __bf16 bf16x8 __attribute__((ext_vector_type(8)));
typedef float floatx4 __attribute__((ext_vector_type(4)));

#define LDW 136  // activation row stride
#define PXW 8    // pre_msg row stride: cols 0..2 recv-x, 3..5 self-x, 6..7 pad

// ws layout (bf16 element offsets). Big mats: Wt[n][k]. K32 pads: [128 n][32 k].
// N16 tails: [16 n][128 k].
#define O_E1W2  0
#define O_E2W1  16384
#define O_E2W2  49152
#define O_E3W1  65536
#define O_E3W2  81920
#define O_E4W1  98304
#define O_E4W2  131072
#define O_DM2T0 147456
#define O_DM2T1 163840
#define O_DO1   180224
#define O_DO2   196608
#define O_EWOUT 212992
#define O_DW3   215040
#define O_E1W1P 217088
#define O_M1T0P 221184
#define O_M1T1P 225280
#define O_DO1XP 229376
#define WS_ELEMS 233472

__global__ void prep_kernel(const float* e1w2, const float* e2w1, const float* e2w2,
    const float* e3w1, const float* e3w2, const float* e4w1, const float* e4w2,
    const float* dmsg2, const float* dout1, const float* dout2,
    const float* ew_out, const float* dout_w3, const float* e1w1,
    const float* dmsg_w1, __hip_bfloat16* ws) {
  int idx = blockIdx.x * 256 + threadIdx.x;
  if (idx >= WS_ELEMS) return;
  float v;
  if (idx < O_E2W1)      { int l = idx;           v = e1w2[(l & 127) * 128 + (l >> 7)]; }
  else if (idx < O_E2W2) { int l = idx - O_E2W1;  v = e2w1[(l & 255) * 128 + (l >> 8)]; }
  else if (idx < O_E3W1) { int l = idx - O_E2W2;  v = e2w2[(l & 127) * 128 + (l >> 7)]; }
  else if (idx < O_E3W2) { int l = idx - O_E3W1;  v = e3w1[(l & 127) * 128 + (l >> 7)]; }
  else if (idx < O_E4W1) { int l = idx - O_E3W2;  v = e3w2[(l & 127) * 128 + (l >> 7)]; }
  else if (idx < O_E4W2) { int l = idx - O_E4W1;  v = e4w1[(l & 255) * 128 + (l >> 8)]; }
  else if (idx < O_DM2T0){ int l = idx - O_E4W2;  v = e4w2[(l & 127) * 128 + (l >> 7)]; }
  else if (idx < O_DM2T1){ int l = idx - O_DM2T0; v = dmsg2[(l & 127) * 128 + (l >> 7)]; }
  else if (idx < O_DO1)  { int l = idx - O_DM2T1; v = dmsg2[16384 + (l & 127) * 128 + (l >> 7)]; }
  else if (idx < O_DO2)  { int l = idx - O_DO1;   v = dout1[384 + (l & 127) * 128 + (l >> 7)]; }
  else if (idx < O_EWOUT){ int l = idx - O_DO2;   v = dout2[(l & 127) * 128 + (l >> 7)]; }
  else if (idx < O_DW3)  { int l = idx - O_EWOUT; int n = l >> 7;
                           v = (n < 2) ? ew_out[(l & 127) * 2 + n] : 0.f; }
  else if (idx < O_E1W1P){ int l = idx - O_DW3;   int n = l >> 7;
                           v = (n < 3) ? dout_w3[(l & 127) * 3 + n] : 0.f; }
  else if (idx < O_M1T0P){ int l = idx - O_E1W1P; int n = l >> 5, c = l & 31;
                           v = (c >= 3 && c < 6) ? e1w1[(c - 3) * 128 + n] : 0.f; }
  else if (idx < O_M1T1P){ int l = idx - O_M1T0P; int n = l >> 5, c = l & 31;
                           v = (c < 6) ? dmsg_w1[c * 128 + n] : 0.f; }
  else if (idx < O_DO1XP){ int l = idx - O_M1T1P; int n = l >> 5, c = l & 31;
                           v = (c < 6) ? dmsg_w1[768 + c * 128 + n] : 0.f; }
  else                   { int l = idx - O_DO1XP; int n = l >> 5, c = l & 31;
                           v = (c >= 3 && c < 6) ? dout1[(c - 3) * 128 + n] : 0.f; }
  ws[idx] = __float2bfloat16(v);
}

struct W4 { bf16x8 b[4]; };
struct W8 { bf16x8 b[8]; };

// R10 structure, slimmed LDS (53.25KB) -> 3 blocks/CU (24 waves):
//  - biases read direct from global, prefetched one stage ahead
//  - pxb PXW=8 (quads 1..3 use zero A-frags; same math as zero-pad)
//  - no xs/obuf; s15 reads x / writes out directly
__global__ __launch_bounds__(512, 6) void nri_fused(
    const float* __restrict__ x,
    const float* __restrict__ e1b1, const float* __restrict__ e1b2,
    const float* __restrict__ e2b1, const float* __restrict__ e2b2,
    const float* __restrict__ e3b1, const float* __restrict__ e3b2,
    const float* __restrict__ e4b1, const float* __restrict__ e4b2,
    const float* __restrict__ eb_out,
    const float* __restrict__ dmsg_b1, const float* __restrict__ dmsg_b2,
    const float* __restrict__ dout_b1, const float* __restrict__ dout_b2,
    const float* __restrict__ dout_b3,
    const __bf16* __restrict__ wt, float* __restrict__ out)
{
  const int tid  = threadIdx.x;
  const int wave = tid >> 6;
  const int lane = tid & 63;
  const int nl   = lane & 15;
  const int quad = lane >> 4;
  const int colb = wave * 16 + nl;  // this wave's output column
  const int gx   = blockIdx.x * 288;

  __shared__ __align__(16) __hip_bfloat16 bufA[96 * LDW];   // 26112 B
  __shared__ __align__(16) __hip_bfloat16 bufB[96 * LDW];   // 26112 B
  __shared__ __align__(16) __hip_bfloat16 pxb[96 * PXW];    // 1536 B
  __shared__ float rtw[192];                                // 768 B

  // ---- early global prefetch (no LDS dependency) ----
  float b_s1 = e1b1[colb];
  bf16x8 wk_s1 = *(const bf16x8*)(wt + O_E1W1P + colb * 32 + quad * 8);

  // ---- stage 0: pre_msg staging only (grid-stride: R6 lesson) ----
  for (int i = tid; i < 96 * PXW; i += 512) {
    int row = i >> 3, c = i & 7;
    int e = row % 6;
    float v = 0.f;
    if (c < 3)      { int rr = row + ((e == 5) ? -5 : 1); v = x[gx + rr * 3 + c]; }
    else if (c < 6) v = x[gx + row * 3 + (c - 3)];
    pxb[i] = __float2bfloat16(v);
  }
  __syncthreads();

  auto initv = [&](floatx4 (&a)[6], float bv) {
    floatx4 v = {bv, bv, bv, bv};
#pragma unroll
    for (int mt = 0; mt < 6; ++mt) a[mt] = v;
  };

  auto loadW128 = [&](int wofs) {
    W4 w;
    const __bf16* p = wt + wofs + colb * 128 + quad * 8;
#pragma unroll
    for (int ks = 0; ks < 4; ++ks) w.b[ks] = *(const bf16x8*)(p + ks * 32);
    return w;
  };
  auto loadW256 = [&](int wofs) {
    W8 w;
    const __bf16* p = wt + wofs + colb * 256 + quad * 8;
#pragma unroll
    for (int ks = 0; ks < 8; ++ks) w.b[ks] = *(const bf16x8*)(p + ks * 32);
    return w;
  };
  auto loadW256half = [&](int wofs, int kh) {
    W4 w;
    const __bf16* p = wt + wofs + colb * 256 + kh * 128 + quad * 8;
#pragma unroll
    for (int ks = 0; ks < 4; ++ks) w.b[ks] = *(const bf16x8*)(p + ks * 32);
    return w;
  };

  auto gemmP = [&](floatx4 (&acc)[6], const W4& w, const __hip_bfloat16* in) {
    const __bf16* ab = (const __bf16*)(const void*)in;
#pragma unroll
    for (int ks = 0; ks < 4; ++ks) {
      int kk = ks * 32 + quad * 8;
#pragma unroll
      for (int mt = 0; mt < 6; ++mt) {
        bf16x8 a = *(const bf16x8*)(ab + (mt * 16 + nl) * LDW + kk);
        acc[mt] = __builtin_amdgcn_mfma_f32_16x16x32_bf16(a, w.b[ks], acc[mt], 0, 0, 0);
      }
    }
  };
  auto gemmP2 = [&](floatx4 (&accA)[6], const W4& wA, floatx4 (&accB)[6],
                    const W4& wB, const __hip_bfloat16* in) {
    const __bf16* ab = (const __bf16*)(const void*)in;
#pragma unroll
    for (int ks = 0; ks < 4; ++ks) {
      int kk = ks * 32 + quad * 8;
#pragma unroll
      for (int mt = 0; mt < 6; ++mt) {
        bf16x8 a = *(const bf16x8*)(ab + (mt * 16 + nl) * LDW + kk);
        accA[mt] = __builtin_amdgcn_mfma_f32_16x16x32_bf16(a, wA.b[ks], accA[mt], 0, 0, 0);
        accB[mt] = __builtin_amdgcn_mfma_f32_16x16x32_bf16(a, wB.b[ks], accB[mt], 0, 0, 0);
      }
    }
  };
  auto gemm256P = [&](floatx4 (&acc)[6], const W8& w, const __hip_bfloat16* in) {
    int rofs0[6], rofs1[6];
#pragma unroll
    for (int mt = 0; mt < 6; ++mt) {
      int r = mt * 16 + nl;
      rofs1[mt] = r * LDW;
      int e = r % 6;
      rofs0[mt] = (r + ((e == 5) ? -5 : 1)) * LDW;
    }
    const __bf16* ab = (const __bf16*)(const void*)in;
#pragma unroll
    for (int ks = 0; ks < 8; ++ks) {
      int kk = (ks & 3) * 32 + quad * 8;
      const int* rofs = (ks < 4) ? rofs0 : rofs1;
#pragma unroll
      for (int mt = 0; mt < 6; ++mt) {
        bf16x8 a = *(const bf16x8*)(ab + rofs[mt] + kk);
        acc[mt] = __builtin_amdgcn_mfma_f32_16x16x32_bf16(a, w.b[ks], acc[mt], 0, 0, 0);
      }
    }
  };
  // K=32 GEMM vs pxb: only quad 0 carries data (k=0..7); quads 1..3 are zero.
  auto gemm32 = [&](floatx4 (&acc)[6], bf16x8 wfrag) {
    const __bf16* pb = (const __bf16*)(const void*)pxb;
#pragma unroll
    for (int mt = 0; mt < 6; ++mt) {
      bf16x8 a = {0, 0, 0, 0, 0, 0, 0, 0};
      if (quad == 0) a = *(const bf16x8*)(pb + (mt * 16 + nl) * PXW);
      acc[mt] = __builtin_amdgcn_mfma_f32_16x16x32_bf16(a, wfrag, acc[mt], 0, 0, 0);
    }
  };
  auto store_act = [&](floatx4 (&acc)[6], int act, __hip_bfloat16* ob) {
#pragma unroll
    for (int mt = 0; mt < 6; ++mt)
#pragma unroll
      for (int r = 0; r < 4; ++r) {
        float z = acc[mt][r];
        if (act == 1) z = (z > 0.f) ? z : (__expf(z) - 1.f);
        else z = fmaxf(z, 0.f);
        ob[(mt * 16 + quad * 4 + r) * LDW + colb] = __float2bfloat16(z);
      }
  };

  floatx4 acc[6], acc2[6];

  // s1: hh = ELU(x @ e1w1 + b) [K32]; prefetch e1w2 + e1b2
  initv(acc, b_s1); gemm32(acc, wk_s1);
  W4 w2 = loadW128(O_E1W2);
  float b_s2 = e1b2[colb];
  store_act(acc, 1, bufA);
  __syncthreads();
  // s2: h = ELU(. @ e1w2 + b); prefetch e2w1 (K256) + e2b1
  initv(acc, b_s2); gemmP(acc, w2, bufA);
  W8 w3 = loadW256(O_E2W1);
  float b_s3 = e2b1[colb];
  store_act(acc, 1, bufB);
  __syncthreads();
  // s3: ELU([h_recv|h] @ e2w1 + b); prefetch e2w2 + e2b2
  initv(acc, b_s3); gemm256P(acc, w3, bufB);
  W4 w4 = loadW128(O_E2W2);
  float b_s4 = e2b2[colb];
  store_act(acc, 1, bufA);
  __syncthreads();
  // s4: he = ELU(. @ e2w2 + b) -> bufB; prefetch e3w1 + e4w1[128:] + biases
  initv(acc, b_s4); gemmP(acc, w4, bufA);
  W4 w5 = loadW128(O_E3W1);
  W4 w5b = loadW256half(O_E4W1, 1);
  float b_s5 = e3b1[colb];
  float b2_s5 = e4b1[colb];
  store_act(acc, 1, bufB);
  __syncthreads();
  // s5: t1 = ELU(he @ e3w1 + b) -> bufA; acc2 = e4b1 + he @ e4w1[128:] (kept)
  initv(acc, b_s5); initv(acc2, b2_s5);
  gemmP2(acc, w5, acc2, w5b, bufB);
  W4 w6 = loadW128(O_E3W2);
  float b_s6 = e3b2[colb];
  store_act(acc, 1, bufA);
  __syncthreads();
  // s6: h2 = ELU(t1 @ e3w2 + b) -> bufB (he dead); prefetch e4w1[:128]
  initv(acc, b_s6); gemmP(acc, w6, bufA);
  W4 w7 = loadW256half(O_E4W1, 0);
  store_act(acc, 1, bufB);
  __syncthreads();
  // s7: h3h = ELU(acc2 + h2 @ e4w1[:128]) -> bufA; prefetch e4w2 + e4b2
  gemmP(acc2, w7, bufB);
  W4 w8 = loadW128(O_E4W2);
  float b_s8 = e4b2[colb];
  store_act(acc2, 1, bufA);
  __syncthreads();
  // s8: h3 = ELU(. @ e4w2 + b) -> bufB; prefetch s9/s10 small weights+biases
  initv(acc, b_s8); gemmP(acc, w8, bufA);
  float ebv = (nl < 2) ? eb_out[nl] : 0.f;
  bf16x8 wk10a = *(const bf16x8*)(wt + O_M1T0P + colb * 32 + quad * 8);
  bf16x8 wk10b = *(const bf16x8*)(wt + O_M1T1P + colb * 32 + quad * 8);
  float b_m0 = dmsg_b1[colb];
  float b_m1 = dmsg_b1[128 + colb];
  store_act(acc, 1, bufB);
  __syncthreads();

  // s9: logits via N=16-padded MFMA tail (waves 0..5, one row-tile each)
  if (wave < 6) {
    int tile = wave;
    floatx4 lg = {ebv, ebv, ebv, ebv};
    const __bf16* ab = (const __bf16*)(const void*)bufB;
    const __bf16* wp = wt + O_EWOUT + nl * 128 + quad * 8;
#pragma unroll
    for (int ks = 0; ks < 4; ++ks) {
      bf16x8 a = *(const bf16x8*)(ab + (tile * 16 + nl) * LDW + ks * 32 + quad * 8);
      bf16x8 b = *(const bf16x8*)(wp + ks * 32);
      lg = __builtin_amdgcn_mfma_f32_16x16x32_bf16(a, b, lg, 0, 0, 0);
    }
    if (nl < 2) {
#pragma unroll
      for (int r = 0; r < 4; ++r)
        rtw[(tile * 16 + quad * 4 + r) * 2 + nl] = lg[r];
    }
  }
  __syncthreads();

  // s10: softmax + m1 both types [K32]: t0->bufA, t1->bufB; prefetch dm2
  if (tid < 96) {
    float l0 = rtw[tid * 2], l1 = rtw[tid * 2 + 1];
    float mx = fmaxf(l0, l1);
    float ea = __expf(l0 - mx), eb = __expf(l1 - mx);
    float inv = 1.f / (ea + eb);
    rtw[tid * 2] = ea * inv; rtw[tid * 2 + 1] = eb * inv;
  }
  initv(acc, b_m0);  gemm32(acc, wk10a);  store_act(acc, 2, bufA);
  initv(acc2, b_m1); gemm32(acc2, wk10b); store_act(acc2, 2, bufB);
  W4 wm0 = loadW128(O_DM2T0);
  W4 wm1 = loadW128(O_DM2T1);
  float b_d0 = dmsg_b2[colb];
  float b_d1 = dmsg_b2[128 + colb];
  __syncthreads();

  // s11: msg = rt0*relu(m1t0 @ w2t0 + b) + rt1*relu(m1t1 @ w2t1 + b)
  initv(acc, b_d0);  gemmP(acc, wm0, bufA);
  initv(acc2, b_d1); gemmP(acc2, wm1, bufB);
#pragma unroll
  for (int mt = 0; mt < 6; ++mt)
#pragma unroll
    for (int r = 0; r < 4; ++r) {
      int row = mt * 16 + quad * 4 + r;
      float r0 = rtw[row * 2], r1 = rtw[row * 2 + 1];
      acc[mt][r] = r0 * fmaxf(acc[mt][r], 0.f) + r1 * fmaxf(acc2[mt][r], 0.f);
    }
  W4 wd1 = loadW128(O_DO1);
  bf16x8 wk13 = *(const bf16x8*)(wt + O_DO1XP + colb * 32 + quad * 8);
  float b_p1 = dout_b1[colb];
  __syncthreads();

  // s12: agg (edge e -> node (e+1)%6) -> bufA
#pragma unroll
  for (int mt = 0; mt < 6; ++mt)
#pragma unroll
    for (int r = 0; r < 4; ++r) {
      int row = mt * 16 + quad * 4 + r;
      int e = row % 6;
      int orow = row + ((e == 5) ? -5 : 1);
      bufA[orow * LDW + colb] = __float2bfloat16(acc[mt][r]);
    }
  __syncthreads();

  // s13: p1 = relu([x|agg] @ d_out_w1 + b) -> bufB; prefetch d_out_w2 + b2
  initv(acc, b_p1); gemmP(acc, wd1, bufA); gemm32(acc, wk13);
  W4 wd2 = loadW128(O_DO2);
  float b_p2 = dout_b2[colb];
  store_act(acc, 2, bufB);
  __syncthreads();
  // s14: p2 = relu(. @ d_out_w2 + b) -> bufA; prefetch b3
  initv(acc, b_p2); gemmP(acc, wd2, bufB);
  float b3v = (nl < 3) ? dout_b3[nl] : 0.f;
  store_act(acc, 2, bufA);
  __syncthreads();

  // s15: out = x + p2 @ d_out_w3 + b3; direct global store (no obuf, no barrier)
  if (wave < 6) {
    int tile = wave;
    floatx4 d = {b3v, b3v, b3v, b3v};
    const __bf16* ab = (const __bf16*)(const void*)bufA;
    const __bf16* wp = wt + O_DW3 + nl * 128 + quad * 8;
#pragma unroll
    for (int ks = 0; ks < 4; ++ks) {
      bf16x8 a = *(const bf16x8*)(ab + (tile * 16 + nl) * LDW + ks * 32 + quad * 8);
      bf16x8 b = *(const bf16x8*)(wp + ks * 32);
      d = __builtin_amdgcn_mfma_f32_16x16x32_bf16(a, b, d, 0, 0, 0);
    }
    if (nl < 3) {
#pragma unroll
      for (int r = 0; r < 4; ++r) {
        int row = tile * 16 + quad * 4 + r;
        out[gx + row * 3 + nl] = x[gx + row * 3 + nl] + d[r];
      }
    }
  }
}

extern "C" void kernel_launch(void* const* d_in, const int* in_sizes, int n_in,
                              void* d_out, int out_size, void* d_ws, size_t ws_size,
                              hipStream_t stream) {
  const float* x       = (const float*)d_in[0];
  const float* e1w1    = (const float*)d_in[3];
  const float* e1b1    = (const float*)d_in[4];
  const float* e1w2    = (const float*)d_in[5];
  const float* e1b2    = (const float*)d_in[6];
  const float* e2w1    = (const float*)d_in[7];
  const float* e2b1    = (const float*)d_in[8];
  const float* e2w2    = (const float*)d_in[9];
  const float* e2b2    = (const float*)d_in[10];
  const float* e3w1    = (const float*)d_in[11];
  const float* e3b1    = (const float*)d_in[12];
  const float* e3w2    = (const float*)d_in[13];
  const float* e3b2    = (const float*)d_in[14];
  const float* e4w1    = (const float*)d_in[15];
  const float* e4b1    = (const float*)d_in[16];
  const float* e4w2    = (const float*)d_in[17];
  const float* e4b2    = (const float*)d_in[18];
  const float* ew_out  = (const float*)d_in[19];
  const float* eb_out  = (const float*)d_in[20];
  const float* dmsg_w1 = (const float*)d_in[21];
  const float* dmsg_b1 = (const float*)d_in[22];
  const float* dmsg_w2 = (const float*)d_in[23];
  const float* dmsg_b2 = (const float*)d_in[24];
  const float* dout_w1 = (const float*)d_in[25];
  const float* dout_b1 = (const float*)d_in[26];
  const float* dout_w2 = (const float*)d_in[27];
  const float* dout_b2 = (const float*)d_in[28];
  const float* dout_w3 = (const float*)d_in[29];
  const float* dout_b3 = (const float*)d_in[30];

  prep_kernel<<<(WS_ELEMS + 255) / 256, 256, 0, stream>>>(
      e1w2, e2w1, e2w2, e3w1, e3w2, e4w1, e4w2, dmsg_w2, dout_w1, dout_w2,
      ew_out, dout_w3, e1w1, dmsg_w1, (__hip_bfloat16*)d_ws);

  nri_fused<<<32768 / 16, 512, 0, stream>>>(
      x, e1b1, e1b2, e2b1, e2b2, e3b1, e3b2, e4b1, e4b2, eb_out,
      dmsg_b1, dmsg_b2, dout_b1, dout_b2, dout_b3,
      (const __bf16*)d_ws, (float*)d_out);
}

// Round 13
// 266.757 us; speedup vs baseline: 1.1916x; 1.1916x over previous
//
#include <hip/hip_runtime.h>
#include <hip/hip_bf16.h>

typedef __bf16 bf16x8 __attribute__((ext_vector_type(8)));
typedef float floatx4 __attribute__((ext_vector_type(4)));

#define LDW 136  // activation row stride
#define PXW 8    // pre_msg row stride: cols 0..2 recv-x, 3..5 self-x, 6..7 pad

// ws layout (bf16 element offsets). Big mats: Wt[n][k]. K32 pads: [128 n][32 k].
// N16 tails: [16 n][128 k].
#define O_E1W2  0
#define O_E2W1  16384
#define O_E2W2  49152
#define O_E3W1  65536
#define O_E3W2  81920
#define O_E4W1  98304
#define O_E4W2  131072
#define O_DM2T0 147456
#define O_DM2T1 163840
#define O_DO1   180224
#define O_DO2   196608
#define O_EWOUT 212992
#define O_DW3   215040
#define O_E1W1P 217088
#define O_M1T0P 221184
#define O_M1T1P 225280
#define O_DO1XP 229376
#define WS_ELEMS 233472

__global__ void prep_kernel(const float* e1w2, const float* e2w1, const float* e2w2,
    const float* e3w1, const float* e3w2, const float* e4w1, const float* e4w2,
    const float* dmsg2, const float* dout1, const float* dout2,
    const float* ew_out, const float* dout_w3, const float* e1w1,
    const float* dmsg_w1, __hip_bfloat16* ws) {
  int idx = blockIdx.x * 256 + threadIdx.x;
  if (idx >= WS_ELEMS) return;
  float v;
  if (idx < O_E2W1)      { int l = idx;           v = e1w2[(l & 127) * 128 + (l >> 7)]; }
  else if (idx < O_E2W2) { int l = idx - O_E2W1;  v = e2w1[(l & 255) * 128 + (l >> 8)]; }
  else if (idx < O_E3W1) { int l = idx - O_E2W2;  v = e2w2[(l & 127) * 128 + (l >> 7)]; }
  else if (idx < O_E3W2) { int l = idx - O_E3W1;  v = e3w1[(l & 127) * 128 + (l >> 7)]; }
  else if (idx < O_E4W1) { int l = idx - O_E3W2;  v = e3w2[(l & 127) * 128 + (l >> 7)]; }
  else if (idx < O_E4W2) { int l = idx - O_E4W1;  v = e4w1[(l & 255) * 128 + (l >> 8)]; }
  else if (idx < O_DM2T0){ int l = idx - O_E4W2;  v = e4w2[(l & 127) * 128 + (l >> 7)]; }
  else if (idx < O_DM2T1){ int l = idx - O_DM2T0; v = dmsg2[(l & 127) * 128 + (l >> 7)]; }
  else if (idx < O_DO1)  { int l = idx - O_DM2T1; v = dmsg2[16384 + (l & 127) * 128 + (l >> 7)]; }
  else if (idx < O_DO2)  { int l = idx - O_DO1;   v = dout1[384 + (l & 127) * 128 + (l >> 7)]; }
  else if (idx < O_EWOUT){ int l = idx - O_DO2;   v = dout2[(l & 127) * 128 + (l >> 7)]; }
  else if (idx < O_DW3)  { int l = idx - O_EWOUT; int n = l >> 7;
                           v = (n < 2) ? ew_out[(l & 127) * 2 + n] : 0.f; }
  else if (idx < O_E1W1P){ int l = idx - O_DW3;   int n = l >> 7;
                           v = (n < 3) ? dout_w3[(l & 127) * 3 + n] : 0.f; }
  else if (idx < O_M1T0P){ int l = idx - O_E1W1P; int n = l >> 5, c = l & 31;
                           v = (c >= 3 && c < 6) ? e1w1[(c - 3) * 128 + n] : 0.f; }
  else if (idx < O_M1T1P){ int l = idx - O_M1T0P; int n = l >> 5, c = l & 31;
                           v = (c < 6) ? dmsg_w1[c * 128 + n] : 0.f; }
  else if (idx < O_DO1XP){ int l = idx - O_M1T1P; int n = l >> 5, c = l & 31;
                           v = (c < 6) ? dmsg_w1[768 + c * 128 + n] : 0.f; }
  else                   { int l = idx - O_DO1XP; int n = l >> 5, c = l & 31;
                           v = (c >= 3 && c < 6) ? dout1[(c - 3) * 128 + n] : 0.f; }
  ws[idx] = __float2bfloat16(v);
}

struct W4 { bf16x8 b[4]; };
struct W8 { bf16x8 b[8]; };

// R12 slimming (54.1KB LDS) + R10's proven launch bounds (512,4):
// VGPR stays ~64 < 85 so 3 blocks/CU come from actual usage, not a clamp.
// rtw stored bf16 to get request+runtime-pad under the 54613B 3-block line.
__global__ __launch_bounds__(512, 4) void nri_fused(
    const float* __restrict__ x,
    const float* __restrict__ e1b1, const float* __restrict__ e1b2,
    const float* __restrict__ e2b1, const float* __restrict__ e2b2,
    const float* __restrict__ e3b1, const float* __restrict__ e3b2,
    const float* __restrict__ e4b1, const float* __restrict__ e4b2,
    const float* __restrict__ eb_out,
    const float* __restrict__ dmsg_b1, const float* __restrict__ dmsg_b2,
    const float* __restrict__ dout_b1, const float* __restrict__ dout_b2,
    const float* __restrict__ dout_b3,
    const __bf16* __restrict__ wt, float* __restrict__ out)
{
  const int tid  = threadIdx.x;
  const int wave = tid >> 6;
  const int lane = tid & 63;
  const int nl   = lane & 15;
  const int quad = lane >> 4;
  const int colb = wave * 16 + nl;  // this wave's output column
  const int gx   = blockIdx.x * 288;

  __shared__ __align__(16) __hip_bfloat16 bufA[96 * LDW];   // 26112 B
  __shared__ __align__(16) __hip_bfloat16 bufB[96 * LDW];   // 26112 B
  __shared__ __align__(16) __hip_bfloat16 pxb[96 * PXW];    // 1536 B
  __shared__ __hip_bfloat16 rtw[192];                        // 384 B

  // ---- early global prefetch (no LDS dependency) ----
  float b_s1 = e1b1[colb];
  bf16x8 wk_s1 = *(const bf16x8*)(wt + O_E1W1P + colb * 32 + quad * 8);

  // ---- stage 0: pre_msg staging only (grid-stride: R6 lesson) ----
  for (int i = tid; i < 96 * PXW; i += 512) {
    int row = i >> 3, c = i & 7;
    int e = row % 6;
    float v = 0.f;
    if (c < 3)      { int rr = row + ((e == 5) ? -5 : 1); v = x[gx + rr * 3 + c]; }
    else if (c < 6) v = x[gx + row * 3 + (c - 3)];
    pxb[i] = __float2bfloat16(v);
  }
  __syncthreads();

  auto initv = [&](floatx4 (&a)[6], float bv) {
    floatx4 v = {bv, bv, bv, bv};
#pragma unroll
    for (int mt = 0; mt < 6; ++mt) a[mt] = v;
  };

  auto loadW128 = [&](int wofs) {
    W4 w;
    const __bf16* p = wt + wofs + colb * 128 + quad * 8;
#pragma unroll
    for (int ks = 0; ks < 4; ++ks) w.b[ks] = *(const bf16x8*)(p + ks * 32);
    return w;
  };
  auto loadW256 = [&](int wofs) {
    W8 w;
    const __bf16* p = wt + wofs + colb * 256 + quad * 8;
#pragma unroll
    for (int ks = 0; ks < 8; ++ks) w.b[ks] = *(const bf16x8*)(p + ks * 32);
    return w;
  };
  auto loadW256half = [&](int wofs, int kh) {
    W4 w;
    const __bf16* p = wt + wofs + colb * 256 + kh * 128 + quad * 8;
#pragma unroll
    for (int ks = 0; ks < 4; ++ks) w.b[ks] = *(const bf16x8*)(p + ks * 32);
    return w;
  };

  auto gemmP = [&](floatx4 (&acc)[6], const W4& w, const __hip_bfloat16* in) {
    const __bf16* ab = (const __bf16*)(const void*)in;
#pragma unroll
    for (int ks = 0; ks < 4; ++ks) {
      int kk = ks * 32 + quad * 8;
#pragma unroll
      for (int mt = 0; mt < 6; ++mt) {
        bf16x8 a = *(const bf16x8*)(ab + (mt * 16 + nl) * LDW + kk);
        acc[mt] = __builtin_amdgcn_mfma_f32_16x16x32_bf16(a, w.b[ks], acc[mt], 0, 0, 0);
      }
    }
  };
  auto gemmP2 = [&](floatx4 (&accA)[6], const W4& wA, floatx4 (&accB)[6],
                    const W4& wB, const __hip_bfloat16* in) {
    const __bf16* ab = (const __bf16*)(const void*)in;
#pragma unroll
    for (int ks = 0; ks < 4; ++ks) {
      int kk = ks * 32 + quad * 8;
#pragma unroll
      for (int mt = 0; mt < 6; ++mt) {
        bf16x8 a = *(const bf16x8*)(ab + (mt * 16 + nl) * LDW + kk);
        accA[mt] = __builtin_amdgcn_mfma_f32_16x16x32_bf16(a, wA.b[ks], accA[mt], 0, 0, 0);
        accB[mt] = __builtin_amdgcn_mfma_f32_16x16x32_bf16(a, wB.b[ks], accB[mt], 0, 0, 0);
      }
    }
  };
  auto gemm256P = [&](floatx4 (&acc)[6], const W8& w, const __hip_bfloat16* in) {
    int rofs0[6], rofs1[6];
#pragma unroll
    for (int mt = 0; mt < 6; ++mt) {
      int r = mt * 16 + nl;
      rofs1[mt] = r * LDW;
      int e = r % 6;
      rofs0[mt] = (r + ((e == 5) ? -5 : 1)) * LDW;
    }
    const __bf16* ab = (const __bf16*)(const void*)in;
#pragma unroll
    for (int ks = 0; ks < 8; ++ks) {
      int kk = (ks & 3) * 32 + quad * 8;
      const int* rofs = (ks < 4) ? rofs0 : rofs1;
#pragma unroll
      for (int mt = 0; mt < 6; ++mt) {
        bf16x8 a = *(const bf16x8*)(ab + rofs[mt] + kk);
        acc[mt] = __builtin_amdgcn_mfma_f32_16x16x32_bf16(a, w.b[ks], acc[mt], 0, 0, 0);
      }
    }
  };
  // K=32 GEMM vs pxb: only quad 0 carries data (k=0..7); quads 1..3 are zero.
  auto gemm32 = [&](floatx4 (&acc)[6], bf16x8 wfrag) {
    const __bf16* pb = (const __bf16*)(const void*)pxb;
#pragma unroll
    for (int mt = 0; mt < 6; ++mt) {
      bf16x8 a = {0, 0, 0, 0, 0, 0, 0, 0};
      if (quad == 0) a = *(const bf16x8*)(pb + (mt * 16 + nl) * PXW);
      acc[mt] = __builtin_amdgcn_mfma_f32_16x16x32_bf16(a, wfrag, acc[mt], 0, 0, 0);
    }
  };
  auto store_act = [&](floatx4 (&acc)[6], int act, __hip_bfloat16* ob) {
#pragma unroll
    for (int mt = 0; mt < 6; ++mt)
#pragma unroll
      for (int r = 0; r < 4; ++r) {
        float z = acc[mt][r];
        if (act == 1) z = (z > 0.f) ? z : (__expf(z) - 1.f);
        else z = fmaxf(z, 0.f);
        ob[(mt * 16 + quad * 4 + r) * LDW + colb] = __float2bfloat16(z);
      }
  };

  floatx4 acc[6], acc2[6];

  // s1: hh = ELU(x @ e1w1 + b) [K32]; prefetch e1w2 + e1b2
  initv(acc, b_s1); gemm32(acc, wk_s1);
  W4 w2 = loadW128(O_E1W2);
  float b_s2 = e1b2[colb];
  store_act(acc, 1, bufA);
  __syncthreads();
  // s2: h = ELU(. @ e1w2 + b); prefetch e2w1 (K256) + e2b1
  initv(acc, b_s2); gemmP(acc, w2, bufA);
  W8 w3 = loadW256(O_E2W1);
  float b_s3 = e2b1[colb];
  store_act(acc, 1, bufB);
  __syncthreads();
  // s3: ELU([h_recv|h] @ e2w1 + b); prefetch e2w2 + e2b2
  initv(acc, b_s3); gemm256P(acc, w3, bufB);
  W4 w4 = loadW128(O_E2W2);
  float b_s4 = e2b2[colb];
  store_act(acc, 1, bufA);
  __syncthreads();
  // s4: he = ELU(. @ e2w2 + b) -> bufB; prefetch e3w1 + e4w1[128:] + biases
  initv(acc, b_s4); gemmP(acc, w4, bufA);
  W4 w5 = loadW128(O_E3W1);
  W4 w5b = loadW256half(O_E4W1, 1);
  float b_s5 = e3b1[colb];
  float b2_s5 = e4b1[colb];
  store_act(acc, 1, bufB);
  __syncthreads();
  // s5: t1 = ELU(he @ e3w1 + b) -> bufA; acc2 = e4b1 + he @ e4w1[128:] (kept)
  initv(acc, b_s5); initv(acc2, b2_s5);
  gemmP2(acc, w5, acc2, w5b, bufB);
  W4 w6 = loadW128(O_E3W2);
  float b_s6 = e3b2[colb];
  store_act(acc, 1, bufA);
  __syncthreads();
  // s6: h2 = ELU(t1 @ e3w2 + b) -> bufB (he dead); prefetch e4w1[:128]
  initv(acc, b_s6); gemmP(acc, w6, bufA);
  W4 w7 = loadW256half(O_E4W1, 0);
  store_act(acc, 1, bufB);
  __syncthreads();
  // s7: h3h = ELU(acc2 + h2 @ e4w1[:128]) -> bufA; prefetch e4w2 + e4b2
  gemmP(acc2, w7, bufB);
  W4 w8 = loadW128(O_E4W2);
  float b_s8 = e4b2[colb];
  store_act(acc2, 1, bufA);
  __syncthreads();
  // s8: h3 = ELU(. @ e4w2 + b) -> bufB; prefetch s9/s10 small weights+biases
  initv(acc, b_s8); gemmP(acc, w8, bufA);
  float ebv = (nl < 2) ? eb_out[nl] : 0.f;
  bf16x8 wk10a = *(const bf16x8*)(wt + O_M1T0P + colb * 32 + quad * 8);
  bf16x8 wk10b = *(const bf16x8*)(wt + O_M1T1P + colb * 32 + quad * 8);
  float b_m0 = dmsg_b1[colb];
  float b_m1 = dmsg_b1[128 + colb];
  store_act(acc, 1, bufB);
  __syncthreads();

  // s9: logits via N=16-padded MFMA tail (waves 0..5, one row-tile each)
  if (wave < 6) {
    int tile = wave;
    floatx4 lg = {ebv, ebv, ebv, ebv};
    const __bf16* ab = (const __bf16*)(const void*)bufB;
    const __bf16* wp = wt + O_EWOUT + nl * 128 + quad * 8;
#pragma unroll
    for (int ks = 0; ks < 4; ++ks) {
      bf16x8 a = *(const bf16x8*)(ab + (tile * 16 + nl) * LDW + ks * 32 + quad * 8);
      bf16x8 b = *(const bf16x8*)(wp + ks * 32);
      lg = __builtin_amdgcn_mfma_f32_16x16x32_bf16(a, b, lg, 0, 0, 0);
    }
    if (nl < 2) {
#pragma unroll
      for (int r = 0; r < 4; ++r)
        rtw[(tile * 16 + quad * 4 + r) * 2 + nl] = __float2bfloat16(lg[r]);
    }
  }
  __syncthreads();

  // s10: softmax + m1 both types [K32]: t0->bufA, t1->bufB; prefetch dm2
  if (tid < 96) {
    float l0 = __bfloat162float(rtw[tid * 2]);
    float l1 = __bfloat162float(rtw[tid * 2 + 1]);
    float mx = fmaxf(l0, l1);
    float ea = __expf(l0 - mx), eb = __expf(l1 - mx);
    float inv = 1.f / (ea + eb);
    rtw[tid * 2] = __float2bfloat16(ea * inv);
    rtw[tid * 2 + 1] = __float2bfloat16(eb * inv);
  }
  initv(acc, b_m0);  gemm32(acc, wk10a);  store_act(acc, 2, bufA);
  initv(acc2, b_m1); gemm32(acc2, wk10b); store_act(acc2, 2, bufB);
  W4 wm0 = loadW128(O_DM2T0);
  W4 wm1 = loadW128(O_DM2T1);
  float b_d0 = dmsg_b2[colb];
  float b_d1 = dmsg_b2[128 + colb];
  __syncthreads();

  // s11: msg = rt0*relu(m1t0 @ w2t0 + b) + rt1*relu(m1t1 @ w2t1 + b)
  initv(acc, b_d0);  gemmP(acc, wm0, bufA);
  initv(acc2, b_d1); gemmP(acc2, wm1, bufB);
#pragma unroll
  for (int mt = 0; mt < 6; ++mt)
#pragma unroll
    for (int r = 0; r < 4; ++r) {
      int row = mt * 16 + quad * 4 + r;
      float r0 = __bfloat162float(rtw[row * 2]);
      float r1 = __bfloat162float(rtw[row * 2 + 1]);
      acc[mt][r] = r0 * fmaxf(acc[mt][r], 0.f) + r1 * fmaxf(acc2[mt][r], 0.f);
    }
  W4 wd1 = loadW128(O_DO1);
  bf16x8 wk13 = *(const bf16x8*)(wt + O_DO1XP + colb * 32 + quad * 8);
  float b_p1 = dout_b1[colb];
  __syncthreads();

  // s12: agg (edge e -> node (e+1)%6) -> bufA
#pragma unroll
  for (int mt = 0; mt < 6; ++mt)
#pragma unroll
    for (int r = 0; r < 4; ++r) {
      int row = mt * 16 + quad * 4 + r;
      int e = row % 6;
      int orow = row + ((e == 5) ? -5 : 1);
      bufA[orow * LDW + colb] = __float2bfloat16(acc[mt][r]);
    }
  __syncthreads();

  // s13: p1 = relu([x|agg] @ d_out_w1 + b) -> bufB; prefetch d_out_w2 + b2
  initv(acc, b_p1); gemmP(acc, wd1, bufA); gemm32(acc, wk13);
  W4 wd2 = loadW128(O_DO2);
  float b_p2 = dout_b2[colb];
  store_act(acc, 2, bufB);
  __syncthreads();
  // s14: p2 = relu(. @ d_out_w2 + b) -> bufA; prefetch b3
  initv(acc, b_p2); gemmP(acc, wd2, bufB);
  float b3v = (nl < 3) ? dout_b3[nl] : 0.f;
  store_act(acc, 2, bufA);
  __syncthreads();

  // s15: out = x + p2 @ d_out_w3 + b3; direct global store (no obuf, no barrier)
  if (wave < 6) {
    int tile = wave;
    floatx4 d = {b3v, b3v, b3v, b3v};
    const __bf16* ab = (const __bf16*)(const void*)bufA;
    const __bf16* wp = wt + O_DW3 + nl * 128 + quad * 8;
#pragma unroll
    for (int ks = 0; ks < 4; ++ks) {
      bf16x8 a = *(const bf16x8*)(ab + (tile * 16 + nl) * LDW + ks * 32 + quad * 8);
      bf16x8 b = *(const bf16x8*)(wp + ks * 32);
      d = __builtin_amdgcn_mfma_f32_16x16x32_bf16(a, b, d, 0, 0, 0);
    }
    if (nl < 3) {
#pragma unroll
      for (int r = 0; r < 4; ++r) {
        int row = tile * 16 + quad * 4 + r;
        out[gx + row * 3 + nl] = x[gx + row * 3 + nl] + d[r];
      }
    }
  }
}

extern "C" void kernel_launch(void* const* d_in, const int* in_sizes, int n_in,
                              void* d_out, int out_size, void* d_ws, size_t ws_size,
                              hipStream_t stream) {
  const float* x       = (const float*)d_in[0];
  const float* e1w1    = (const float*)d_in[3];
  const float* e1b1    = (const float*)d_in[4];
  const float* e1w2    = (const float*)d_in[5];
  const float* e1b2    = (const float*)d_in[6];
  const float* e2w1    = (const float*)d_in[7];
  const float* e2b1    = (const float*)d_in[8];
  const float* e2w2    = (const float*)d_in[9];
  const float* e2b2    = (const float*)d_in[10];
  const float* e3w1    = (const float*)d_in[11];
  const float* e3b1    = (const float*)d_in[12];
  const float* e3w2    = (const float*)d_in[13];
  const float* e3b2    = (const float*)d_in[14];
  const float* e4w1    = (const float*)d_in[15];
  const float* e4b1    = (const float*)d_in[16];
  const float* e4w2    = (const float*)d_in[17];
  const float* e4b2    = (const float*)d_in[18];
  const float* ew_out  = (const float*)d_in[19];
  const float* eb_out  = (const float*)d_in[20];
  const float* dmsg_w1 = (const float*)d_in[21];
  const float* dmsg_b1 = (const float*)d_in[22];
  const float* dmsg_w2 = (const float*)d_in[23];
  const float* dmsg_b2 = (const float*)d_in[24];
  const float* dout_w1 = (const float*)d_in[25];
  const float* dout_b1 = (const float*)d_in[26];
  const float* dout_w2 = (const float*)d_in[27];
  const float* dout_b2 = (const float*)d_in[28];
  const float* dout_w3 = (const float*)d_in[29];
  const float* dout_b3 = (const float*)d_in[30];

  prep_kernel<<<(WS_ELEMS + 255) / 256, 256, 0, stream>>>(
      e1w2, e2w1, e2w2, e3w1, e3w2, e4w1, e4w2, dmsg_w2, dout_w1, dout_w2,
      ew_out, dout_w3, e1w1, dmsg_w1, (__hip_bfloat16*)d_ws);

  nri_fused<<<32768 / 16, 512, 0, stream>>>(
      x, e1b1, e1b2, e2b1, e2b2, e3b1, e3b2, e4b1, e4b2, eb_out,
      dmsg_b1, dmsg_b2, dout_b1, dout_b2, dout_b3,
      (const __bf16*)d_ws, (float*)d_out);
}

// Round 14
// 255.098 us; speedup vs baseline: 1.2460x; 1.0457x over previous
//
#include <hip/hip_runtime.h>
#include <hip/hip_bf16.h>

typedef __bf16 bf16x8 __attribute__((ext_vector_type(8)));
typedef __bf16 bf16x4 __attribute__((ext_vector_type(4)));
typedef float floatx4 __attribute__((ext_vector_type(4)));

#define LDW 136  // activation row stride
#define PXW 8    // pre_msg row stride: cols 0..2 recv-x, 3..5 self-x, 6..7 pad

// ws layout (bf16 element offsets). Big mats: Wt[n][k]. K32 pads: [128 n][32 k].
// N16 tails: [16 n][128 k].
#define O_E1W2  0
#define O_E2W1  16384
#define O_E2W2  49152
#define O_E3W1  65536
#define O_E3W2  81920
#define O_E4W1  98304
#define O_E4W2  131072
#define O_DM2T0 147456
#define O_DM2T1 163840
#define O_DO1   180224
#define O_DO2   196608
#define O_EWOUT 212992
#define O_DW3   215040
#define O_E1W1P 217088
#define O_M1T0P 221184
#define O_M1T1P 225280
#define O_DO1XP 229376
#define WS_ELEMS 233472

__global__ void prep_kernel(const float* e1w2, const float* e2w1, const float* e2w2,
    const float* e3w1, const float* e3w2, const float* e4w1, const float* e4w2,
    const float* dmsg2, const float* dout1, const float* dout2,
    const float* ew_out, const float* dout_w3, const float* e1w1,
    const float* dmsg_w1, __hip_bfloat16* ws) {
  int idx = blockIdx.x * 256 + threadIdx.x;
  if (idx >= WS_ELEMS) return;
  float v;
  if (idx < O_E2W1)      { int l = idx;           v = e1w2[(l & 127) * 128 + (l >> 7)]; }
  else if (idx < O_E2W2) { int l = idx - O_E2W1;  v = e2w1[(l & 255) * 128 + (l >> 8)]; }
  else if (idx < O_E3W1) { int l = idx - O_E2W2;  v = e2w2[(l & 127) * 128 + (l >> 7)]; }
  else if (idx < O_E3W2) { int l = idx - O_E3W1;  v = e3w1[(l & 127) * 128 + (l >> 7)]; }
  else if (idx < O_E4W1) { int l = idx - O_E3W2;  v = e3w2[(l & 127) * 128 + (l >> 7)]; }
  else if (idx < O_E4W2) { int l = idx - O_E4W1;  v = e4w1[(l & 255) * 128 + (l >> 8)]; }
  else if (idx < O_DM2T0){ int l = idx - O_E4W2;  v = e4w2[(l & 127) * 128 + (l >> 7)]; }
  else if (idx < O_DM2T1){ int l = idx - O_DM2T0; v = dmsg2[(l & 127) * 128 + (l >> 7)]; }
  else if (idx < O_DO1)  { int l = idx - O_DM2T1; v = dmsg2[16384 + (l & 127) * 128 + (l >> 7)]; }
  else if (idx < O_DO2)  { int l = idx - O_DO1;   v = dout1[384 + (l & 127) * 128 + (l >> 7)]; }
  else if (idx < O_EWOUT){ int l = idx - O_DO2;   v = dout2[(l & 127) * 128 + (l >> 7)]; }
  else if (idx < O_DW3)  { int l = idx - O_EWOUT; int n = l >> 7;
                           v = (n < 2) ? ew_out[(l & 127) * 2 + n] : 0.f; }
  else if (idx < O_E1W1P){ int l = idx - O_DW3;   int n = l >> 7;
                           v = (n < 3) ? dout_w3[(l & 127) * 3 + n] : 0.f; }
  else if (idx < O_M1T0P){ int l = idx - O_E1W1P; int n = l >> 5, c = l & 31;
                           v = (c >= 3 && c < 6) ? e1w1[(c - 3) * 128 + n] : 0.f; }
  else if (idx < O_M1T1P){ int l = idx - O_M1T0P; int n = l >> 5, c = l & 31;
                           v = (c < 6) ? dmsg_w1[c * 128 + n] : 0.f; }
  else if (idx < O_DO1XP){ int l = idx - O_M1T1P; int n = l >> 5, c = l & 31;
                           v = (c < 6) ? dmsg_w1[768 + c * 128 + n] : 0.f; }
  else                   { int l = idx - O_DO1XP; int n = l >> 5, c = l & 31;
                           v = (c >= 3 && c < 6) ? dout1[(c - 3) * 128 + n] : 0.f; }
  ws[idx] = __float2bfloat16(v);
}

struct W4 { bf16x8 b[4]; };
struct W8 { bf16x8 b[8]; };
union PK { bf16x4 v; __hip_bfloat16 h[4]; };

// R13 base + operand swap (weights->A, acts->B). Operand loads are identical
// (A/B fragment layouts are transpose-symmetric); only D flips: lane holds
// act-row mt*16+nl, out-cols wave*16+quad*4+r -> packed b64 epilogue stores.
__global__ __launch_bounds__(512, 4) void nri_fused(
    const float* __restrict__ x,
    const float* __restrict__ e1b1, const float* __restrict__ e1b2,
    const float* __restrict__ e2b1, const float* __restrict__ e2b2,
    const float* __restrict__ e3b1, const float* __restrict__ e3b2,
    const float* __restrict__ e4b1, const float* __restrict__ e4b2,
    const float* __restrict__ eb_out,
    const float* __restrict__ dmsg_b1, const float* __restrict__ dmsg_b2,
    const float* __restrict__ dout_b1, const float* __restrict__ dout_b2,
    const float* __restrict__ dout_b3,
    const __bf16* __restrict__ wt, float* __restrict__ out)
{
  const int tid  = threadIdx.x;
  const int wave = tid >> 6;
  const int lane = tid & 63;
  const int nl   = lane & 15;
  const int quad = lane >> 4;
  const int colb = wave * 16 + nl;        // weight-slice column (for loads)
  const int cq   = wave * 16 + quad * 4;  // this lane's 4 output cols (store)
  const int gx   = blockIdx.x * 288;

  __shared__ __align__(16) __hip_bfloat16 bufA[96 * LDW];   // 26112 B
  __shared__ __align__(16) __hip_bfloat16 bufB[96 * LDW];   // 26112 B
  __shared__ __align__(16) __hip_bfloat16 pxb[96 * PXW];    // 1536 B
  __shared__ __hip_bfloat16 rtw[192];                        // 384 B

  // ---- early global prefetch (no LDS dependency) ----
  floatx4 b_s1 = *(const floatx4*)(e1b1 + cq);
  bf16x8 wk_s1 = *(const bf16x8*)(wt + O_E1W1P + colb * 32 + quad * 8);

  // ---- stage 0: pre_msg staging only (grid-stride: R6 lesson) ----
  for (int i = tid; i < 96 * PXW; i += 512) {
    int row = i >> 3, c = i & 7;
    int e = row % 6;
    float v = 0.f;
    if (c < 3)      { int rr = row + ((e == 5) ? -5 : 1); v = x[gx + rr * 3 + c]; }
    else if (c < 6) v = x[gx + row * 3 + (c - 3)];
    pxb[i] = __float2bfloat16(v);
  }
  __syncthreads();

  auto initv = [&](floatx4 (&a)[6], floatx4 bv) {
#pragma unroll
    for (int mt = 0; mt < 6; ++mt) a[mt] = bv;
  };

  auto loadW128 = [&](int wofs) {
    W4 w;
    const __bf16* p = wt + wofs + colb * 128 + quad * 8;
#pragma unroll
    for (int ks = 0; ks < 4; ++ks) w.b[ks] = *(const bf16x8*)(p + ks * 32);
    return w;
  };
  auto loadW256 = [&](int wofs) {
    W8 w;
    const __bf16* p = wt + wofs + colb * 256 + quad * 8;
#pragma unroll
    for (int ks = 0; ks < 8; ++ks) w.b[ks] = *(const bf16x8*)(p + ks * 32);
    return w;
  };
  auto loadW256half = [&](int wofs, int kh) {
    W4 w;
    const __bf16* p = wt + wofs + colb * 256 + kh * 128 + quad * 8;
#pragma unroll
    for (int ks = 0; ks < 4; ++ks) w.b[ks] = *(const bf16x8*)(p + ks * 32);
    return w;
  };

  // swapped: A = weight frag, B = act frag (identical loads, D transposed)
  auto gemmP = [&](floatx4 (&acc)[6], const W4& w, const __hip_bfloat16* in) {
    const __bf16* ab = (const __bf16*)(const void*)in;
#pragma unroll
    for (int ks = 0; ks < 4; ++ks) {
      int kk = ks * 32 + quad * 8;
#pragma unroll
      for (int mt = 0; mt < 6; ++mt) {
        bf16x8 b = *(const bf16x8*)(ab + (mt * 16 + nl) * LDW + kk);
        acc[mt] = __builtin_amdgcn_mfma_f32_16x16x32_bf16(w.b[ks], b, acc[mt], 0, 0, 0);
      }
    }
  };
  auto gemmP2 = [&](floatx4 (&accA)[6], const W4& wA, floatx4 (&accB)[6],
                    const W4& wB, const __hip_bfloat16* in) {
    const __bf16* ab = (const __bf16*)(const void*)in;
#pragma unroll
    for (int ks = 0; ks < 4; ++ks) {
      int kk = ks * 32 + quad * 8;
#pragma unroll
      for (int mt = 0; mt < 6; ++mt) {
        bf16x8 b = *(const bf16x8*)(ab + (mt * 16 + nl) * LDW + kk);
        accA[mt] = __builtin_amdgcn_mfma_f32_16x16x32_bf16(wA.b[ks], b, accA[mt], 0, 0, 0);
        accB[mt] = __builtin_amdgcn_mfma_f32_16x16x32_bf16(wB.b[ks], b, accB[mt], 0, 0, 0);
      }
    }
  };
  auto gemm256P = [&](floatx4 (&acc)[6], const W8& w, const __hip_bfloat16* in) {
    int rofs0[6], rofs1[6];
#pragma unroll
    for (int mt = 0; mt < 6; ++mt) {
      int r = mt * 16 + nl;
      rofs1[mt] = r * LDW;
      int e = r % 6;
      rofs0[mt] = (r + ((e == 5) ? -5 : 1)) * LDW;
    }
    const __bf16* ab = (const __bf16*)(const void*)in;
#pragma unroll
    for (int ks = 0; ks < 8; ++ks) {
      int kk = (ks & 3) * 32 + quad * 8;
      const int* rofs = (ks < 4) ? rofs0 : rofs1;
#pragma unroll
      for (int mt = 0; mt < 6; ++mt) {
        bf16x8 b = *(const bf16x8*)(ab + rofs[mt] + kk);
        acc[mt] = __builtin_amdgcn_mfma_f32_16x16x32_bf16(w.b[ks], b, acc[mt], 0, 0, 0);
      }
    }
  };
  // K=32 GEMM vs pxb (B operand); only quad 0 carries data, rest zero.
  auto gemm32 = [&](floatx4 (&acc)[6], bf16x8 wfrag) {
    const __bf16* pb = (const __bf16*)(const void*)pxb;
#pragma unroll
    for (int mt = 0; mt < 6; ++mt) {
      bf16x8 b = {0, 0, 0, 0, 0, 0, 0, 0};
      if (quad == 0) b = *(const bf16x8*)(pb + (mt * 16 + nl) * PXW);
      acc[mt] = __builtin_amdgcn_mfma_f32_16x16x32_bf16(wfrag, b, acc[mt], 0, 0, 0);
    }
  };
  // packed b64 epilogue: row = mt*16+nl, cols cq..cq+3
  auto store_act = [&](floatx4 (&acc)[6], int act, __hip_bfloat16* ob) {
#pragma unroll
    for (int mt = 0; mt < 6; ++mt) {
      PK p;
#pragma unroll
      for (int r = 0; r < 4; ++r) {
        float z = acc[mt][r];
        if (act == 1) z = (z > 0.f) ? z : (__expf(z) - 1.f);
        else z = fmaxf(z, 0.f);
        p.h[r] = __float2bfloat16(z);
      }
      *(bf16x4*)((__bf16*)(void*)ob + (mt * 16 + nl) * LDW + cq) = p.v;
    }
  };

  floatx4 acc[6], acc2[6];

  // s1: hh = ELU(x @ e1w1 + b) [K32]; prefetch e1w2 + e1b2
  initv(acc, b_s1); gemm32(acc, wk_s1);
  W4 w2 = loadW128(O_E1W2);
  floatx4 b_s2 = *(const floatx4*)(e1b2 + cq);
  store_act(acc, 1, bufA);
  __syncthreads();
  // s2: h = ELU(. @ e1w2 + b); prefetch e2w1 (K256) + e2b1
  initv(acc, b_s2); gemmP(acc, w2, bufA);
  W8 w3 = loadW256(O_E2W1);
  floatx4 b_s3 = *(const floatx4*)(e2b1 + cq);
  store_act(acc, 1, bufB);
  __syncthreads();
  // s3: ELU([h_recv|h] @ e2w1 + b); prefetch e2w2 + e2b2
  initv(acc, b_s3); gemm256P(acc, w3, bufB);
  W4 w4 = loadW128(O_E2W2);
  floatx4 b_s4 = *(const floatx4*)(e2b2 + cq);
  store_act(acc, 1, bufA);
  __syncthreads();
  // s4: he = ELU(. @ e2w2 + b) -> bufB; prefetch e3w1 + e4w1[128:] + biases
  initv(acc, b_s4); gemmP(acc, w4, bufA);
  W4 w5 = loadW128(O_E3W1);
  W4 w5b = loadW256half(O_E4W1, 1);
  floatx4 b_s5 = *(const floatx4*)(e3b1 + cq);
  floatx4 b2_s5 = *(const floatx4*)(e4b1 + cq);
  store_act(acc, 1, bufB);
  __syncthreads();
  // s5: t1 = ELU(he @ e3w1 + b) -> bufA; acc2 = e4b1 + he @ e4w1[128:] (kept)
  initv(acc, b_s5); initv(acc2, b2_s5);
  gemmP2(acc, w5, acc2, w5b, bufB);
  W4 w6 = loadW128(O_E3W2);
  floatx4 b_s6 = *(const floatx4*)(e3b2 + cq);
  store_act(acc, 1, bufA);
  __syncthreads();
  // s6: h2 = ELU(t1 @ e3w2 + b) -> bufB (he dead); prefetch e4w1[:128]
  initv(acc, b_s6); gemmP(acc, w6, bufA);
  W4 w7 = loadW256half(O_E4W1, 0);
  store_act(acc, 1, bufB);
  __syncthreads();
  // s7: h3h = ELU(acc2 + h2 @ e4w1[:128]) -> bufA; prefetch e4w2 + e4b2
  gemmP(acc2, w7, bufB);
  W4 w8 = loadW128(O_E4W2);
  floatx4 b_s8 = *(const floatx4*)(e4b2 + cq);
  store_act(acc2, 1, bufA);
  __syncthreads();
  // s8: h3 = ELU(. @ e4w2 + b) -> bufB; prefetch s9/s10 small weights+biases
  initv(acc, b_s8); gemmP(acc, w8, bufA);
  float ebv = (nl < 2) ? eb_out[nl] : 0.f;
  bf16x8 wk10a = *(const bf16x8*)(wt + O_M1T0P + colb * 32 + quad * 8);
  bf16x8 wk10b = *(const bf16x8*)(wt + O_M1T1P + colb * 32 + quad * 8);
  floatx4 b_m0 = *(const floatx4*)(dmsg_b1 + cq);
  floatx4 b_m1 = *(const floatx4*)(dmsg_b1 + 128 + cq);
  store_act(acc, 1, bufB);
  __syncthreads();

  // s9: logits via N=16-padded MFMA tail (old orientation; waves 0..5)
  if (wave < 6) {
    int tile = wave;
    floatx4 lg = {ebv, ebv, ebv, ebv};
    const __bf16* ab = (const __bf16*)(const void*)bufB;
    const __bf16* wp = wt + O_EWOUT + nl * 128 + quad * 8;
#pragma unroll
    for (int ks = 0; ks < 4; ++ks) {
      bf16x8 a = *(const bf16x8*)(ab + (tile * 16 + nl) * LDW + ks * 32 + quad * 8);
      bf16x8 b = *(const bf16x8*)(wp + ks * 32);
      lg = __builtin_amdgcn_mfma_f32_16x16x32_bf16(a, b, lg, 0, 0, 0);
    }
    if (nl < 2) {
#pragma unroll
      for (int r = 0; r < 4; ++r)
        rtw[(tile * 16 + quad * 4 + r) * 2 + nl] = __float2bfloat16(lg[r]);
    }
  }
  __syncthreads();

  // s10: softmax + m1 both types [K32]: t0->bufA, t1->bufB; prefetch dm2
  if (tid < 96) {
    float l0 = __bfloat162float(rtw[tid * 2]);
    float l1 = __bfloat162float(rtw[tid * 2 + 1]);
    float mx = fmaxf(l0, l1);
    float ea = __expf(l0 - mx), eb = __expf(l1 - mx);
    float inv = 1.f / (ea + eb);
    rtw[tid * 2] = __float2bfloat16(ea * inv);
    rtw[tid * 2 + 1] = __float2bfloat16(eb * inv);
  }
  initv(acc, b_m0);  gemm32(acc, wk10a);  store_act(acc, 2, bufA);
  initv(acc2, b_m1); gemm32(acc2, wk10b); store_act(acc2, 2, bufB);
  W4 wm0 = loadW128(O_DM2T0);
  W4 wm1 = loadW128(O_DM2T1);
  floatx4 b_d0 = *(const floatx4*)(dmsg_b2 + cq);
  floatx4 b_d1 = *(const floatx4*)(dmsg_b2 + 128 + cq);
  __syncthreads();

  // s11: msg = rt0*relu(m1t0 @ w2t0 + b) + rt1*relu(m1t1 @ w2t1 + b)
  // swapped D: row = mt*16+nl -> one rtw pair per mt (was 24 lookups)
  initv(acc, b_d0);  gemmP(acc, wm0, bufA);
  initv(acc2, b_d1); gemmP(acc2, wm1, bufB);
#pragma unroll
  for (int mt = 0; mt < 6; ++mt) {
    int row = mt * 16 + nl;
    float r0 = __bfloat162float(rtw[row * 2]);
    float r1 = __bfloat162float(rtw[row * 2 + 1]);
#pragma unroll
    for (int r = 0; r < 4; ++r)
      acc[mt][r] = r0 * fmaxf(acc[mt][r], 0.f) + r1 * fmaxf(acc2[mt][r], 0.f);
  }
  W4 wd1 = loadW128(O_DO1);
  bf16x8 wk13 = *(const bf16x8*)(wt + O_DO1XP + colb * 32 + quad * 8);
  floatx4 b_p1 = *(const floatx4*)(dout_b1 + cq);
  __syncthreads();

  // s12: agg (edge e -> node (e+1)%6) -> bufA; packed b64 writes
#pragma unroll
  for (int mt = 0; mt < 6; ++mt) {
    int row = mt * 16 + nl;
    int e = row % 6;
    int orow = row + ((e == 5) ? -5 : 1);
    PK p;
#pragma unroll
    for (int r = 0; r < 4; ++r) p.h[r] = __float2bfloat16(acc[mt][r]);
    *(bf16x4*)((__bf16*)(void*)bufA + orow * LDW + cq) = p.v;
  }
  __syncthreads();

  // s13: p1 = relu([x|agg] @ d_out_w1 + b) -> bufB; prefetch d_out_w2 + b2
  initv(acc, b_p1); gemmP(acc, wd1, bufA); gemm32(acc, wk13);
  W4 wd2 = loadW128(O_DO2);
  floatx4 b_p2 = *(const floatx4*)(dout_b2 + cq);
  store_act(acc, 2, bufB);
  __syncthreads();
  // s14: p2 = relu(. @ d_out_w2 + b) -> bufA; prefetch b3
  initv(acc, b_p2); gemmP(acc, wd2, bufB);
  float b3v = (nl < 3) ? dout_b3[nl] : 0.f;
  store_act(acc, 2, bufA);
  __syncthreads();

  // s15: out = x + p2 @ d_out_w3 + b3 (old orientation; direct global store)
  if (wave < 6) {
    int tile = wave;
    floatx4 d = {b3v, b3v, b3v, b3v};
    const __bf16* ab = (const __bf16*)(const void*)bufA;
    const __bf16* wp = wt + O_DW3 + nl * 128 + quad * 8;
#pragma unroll
    for (int ks = 0; ks < 4; ++ks) {
      bf16x8 a = *(const bf16x8*)(ab + (tile * 16 + nl) * LDW + ks * 32 + quad * 8);
      bf16x8 b = *(const bf16x8*)(wp + ks * 32);
      d = __builtin_amdgcn_mfma_f32_16x16x32_bf16(a, b, d, 0, 0, 0);
    }
    if (nl < 3) {
#pragma unroll
      for (int r = 0; r < 4; ++r) {
        int row = tile * 16 + quad * 4 + r;
        out[gx + row * 3 + nl] = x[gx + row * 3 + nl] + d[r];
      }
    }
  }
}

extern "C" void kernel_launch(void* const* d_in, const int* in_sizes, int n_in,
                              void* d_out, int out_size, void* d_ws, size_t ws_size,
                              hipStream_t stream) {
  const float* x       = (const float*)d_in[0];
  const float* e1w1    = (const float*)d_in[3];
  const float* e1b1    = (const float*)d_in[4];
  const float* e1w2    = (const float*)d_in[5];
  const float* e1b2    = (const float*)d_in[6];
  const float* e2w1    = (const float*)d_in[7];
  const float* e2b1    = (const float*)d_in[8];
  const float* e2w2    = (const float*)d_in[9];
  const float* e2b2    = (const float*)d_in[10];
  const float* e3w1    = (const float*)d_in[11];
  const float* e3b1    = (const float*)d_in[12];
  const float* e3w2    = (const float*)d_in[13];
  const float* e3b2    = (const float*)d_in[14];
  const float* e4w1    = (const float*)d_in[15];
  const float* e4b1    = (const float*)d_in[16];
  const float* e4w2    = (const float*)d_in[17];
  const float* e4b2    = (const float*)d_in[18];
  const float* ew_out  = (const float*)d_in[19];
  const float* eb_out  = (const float*)d_in[20];
  const float* dmsg_w1 = (const float*)d_in[21];
  const float* dmsg_b1 = (const float*)d_in[22];
  const float* dmsg_w2 = (const float*)d_in[23];
  const float* dmsg_b2 = (const float*)d_in[24];
  const float* dout_w1 = (const float*)d_in[25];
  const float* dout_b1 = (const float*)d_in[26];
  const float* dout_w2 = (const float*)d_in[27];
  const float* dout_b2 = (const float*)d_in[28];
  const float* dout_w3 = (const float*)d_in[29];
  const float* dout_b3 = (const float*)d_in[30];

  prep_kernel<<<(WS_ELEMS + 255) / 256, 256, 0, stream>>>(
      e1w2, e2w1, e2w2, e3w1, e3w2, e4w1, e4w2, dmsg_w2, dout_w1, dout_w2,
      ew_out, dout_w3, e1w1, dmsg_w1, (__hip_bfloat16*)d_ws);

  nri_fused<<<32768 / 16, 512, 0, stream>>>(
      x, e1b1, e1b2, e2b1, e2b2, e3b1, e3b2, e4b1, e4b2, eb_out,
      dmsg_b1, dmsg_b2, dout_b1, dout_b2, dout_b3,
      (const __bf16*)d_ws, (float*)d_out);
}